// Round 14
// baseline (139.717 us; speedup 1.0000x reference)
//
#include <hip/hip_runtime.h>
#include <math.h>

#define SC 4
#define BB 2
#define CC 32
#define HH 256
#define WW 512
#define CH (HH / SC)   // 64
#define CW (WW / SC)   // 128

using f16x8 = __attribute__((ext_vector_type(8))) _Float16;
using f16x4 = __attribute__((ext_vector_type(4))) _Float16;
using f32x4 = __attribute__((ext_vector_type(4))) float;
using f32x2 = __attribute__((ext_vector_type(2))) float;

// Direction metadata (output channel order: c, l, r, t, b, lt, rt, lb, rb)
//   s0: 0 -> xv (x[w%4]), 1 -> 4-(w%4) (D1), 2 -> (w%4)+1 (D2)
//   s1: 0 -> yv (x[h%4]), 1 -> 4-(h%4) (D3), 2 -> (h%4)+1 (D4)
constexpr int K_dh[9] = {0, 0, 0, -1, 1, -1, -1, 1, 1};
constexpr int K_dw[9] = {0, -1, 1, 0, 0, -1, 1, -1, 1};
constexpr int K_s0[9] = {0, 1, 2, 0, 0, 1, 2, 0, 0};
constexpr int K_s1[9] = {0, 0, 0, 1, 2, 0, 0, 1, 2};

__device__ __forceinline__ float swz_x16(float v) {
    // lane ^ 16 within each 32-lane half: BitMode offset = (16<<10)|0x1F
    return __int_as_float(__builtin_amdgcn_ds_swizzle(__float_as_int(v), 0x401F));
}

// LESSON (R10/R11/R12 bisect): permlane-swap inline asm with two "+v"
// operands holding equal values can be register-coalesced into a self-swap
// (wrong sums; absmax 1.0). The DS reduce below (swz_x16 + shfl_xor) is the
// proven path; it replicates the full sum into ALL 64 lanes by construction.

// Pre-pass: ALr[(b*CH+cy)*CW+cx][o] = sum_c w0[o*66+c] * lr[b][c][cy][cx]  (fp32)
__global__ __launch_bounds__(256) void alr_prepass(const float* __restrict__ lr,
                                                   const float* __restrict__ w0,
                                                   float* __restrict__ alr) {
    const int idx = blockIdx.x * 256 + threadIdx.x;
    if (idx >= BB * CH * CW) return;
    const int b = idx / (CH * CW);
    const int cell = idx - b * (CH * CW);
    const float* lp = lr + (size_t)b * CC * CH * CW + cell;
    float lv[32];
#pragma unroll
    for (int c = 0; c < 32; c++) lv[c] = lp[(size_t)c * (CH * CW)];
    float acc[32];
#pragma unroll
    for (int o = 0; o < 32; o++) {
        float a = 0.f;
#pragma unroll
        for (int c = 0; c < 32; c++) a = fmaf(lv[c], w0[o * 66 + c], a);
        acc[o] = a;
    }
    float4* op = (float4*)(alr + (size_t)idx * 32);
#pragma unroll
    for (int j = 0; j < 8; j++)
        op[j] = make_float4(acc[4 * j], acc[4 * j + 1], acc[4 * j + 2], acc[4 * j + 3]);
}

// MFMA main, R14 = R13 (PASSING, dur 139.3) + D-GROUPED ILP.
// R13 counters: VALUBusy 36%, VGPR 56/128 — the compiler schedules the
// unrolled d-loop as 9 sequential chains with minimal register lifetime;
// only 2 chains (tiles) overlap in each latency shadow. This round groups
// directions 3-at-a-time and batches phases textually:
//   {6x a1 build} -> {6x MFMA2} -> {6x glue} -> {6x MFMA3} -> {6x reduce}
// -> 6 independent chains in flight. Arithmetic identical, order-only
// change: output bit-identical to R13. Transient regs ~+48 (peak ~104<128);
// persistent state unchanged (unlike R7's quad-tile which grew PERSISTENT
// state and triggered rematerialization).
// Spill tripwire: WRITE_SIZE must stay 9216 KB. Scheduler-took-the-hint
// signature: VGPR ~95-110, VALUBusy up.
// Carried structure (R12/R13): dual-tile (2048 blocks, 256 thr, 4 waves,
// 32 px/wave), f32 s_alr, swapped layer-2 (D2[ch2][px]), in-lane K16
// layer-3 (v_mfma_f32_16x16x16f16, w2A rows>=8 zero), DS layer-4 reduce,
// fused single-softmax tail with lane<32 contiguous stores.
// R3 lesson: __launch_bounds__(256,4), never force 8/EU.
template <bool USE_WS>
__global__ __launch_bounds__(256, 4) void ercm_mfma(const float* __restrict__ hr,
                                                    const float* __restrict__ lr,
                                                    const float* __restrict__ alr,
                                                    const float* __restrict__ w0,
                                                    const float* __restrict__ w1,
                                                    const float* __restrict__ w2,
                                                    const float* __restrict__ w3,
                                                    float* __restrict__ out) {
    __shared__ float    s_alr[30 * 40];     // [cell][o] FP32, 3 x 10 halo, stride 40 (160B rows)
    __shared__ _Float16 s_ahr[4][32 * 40];  // per wave: [px 0..31][o] (both tiles)

    const int tid = threadIdx.x;
    const int lane = tid & 63;
    const int ty = tid >> 6;       // wave id = h-row within block
    const int m16 = lane & 15;
    const int q = lane >> 4;       // quad
    const int bx = blockIdx.x;     // 0..15
    const int by = blockIdx.y;     // 0..63
    const int b = blockIdx.z;      // 0..1
    const int h = by * 4 + ty;
    const int wp0 = bx * 32;
    const size_t HW = (size_t)HH * WW;

    // ---- stage ALr halo tile (3 x 10 coarse cells), FP32 ----
    const int cy0 = by, cx0 = bx * 8;
    if (USE_WS) {
        for (int i = tid; i < 30 * 32; i += 256) {
            const int c = i & 31, cell = i >> 5;
            const int row = cell / 10, col = cell - row * 10;
            const int gcy = cy0 - 1 + row, gcx = cx0 - 1 + col;
            float v = 0.f;
            if ((unsigned)gcy < (unsigned)CH && (unsigned)gcx < (unsigned)CW)
                v = alr[(((size_t)b * CH + gcy) * CW + gcx) * 32 + c];
            s_alr[cell * 40 + c] = v;
        }
    } else {
        for (int i = tid; i < 30 * 32; i += 256) {
            const int o = i & 31, cell = i >> 5;
            const int row = cell / 10, col = cell - row * 10;
            const int gcy = cy0 - 1 + row, gcx = cx0 - 1 + col;
            float a = 0.f;
            if ((unsigned)gcy < (unsigned)CH && (unsigned)gcx < (unsigned)CW) {
                const float* lp = lr + (size_t)b * CC * CH * CW + (size_t)gcy * CW + gcx;
#pragma unroll
                for (int c = 0; c < 32; c++) a = fmaf(lp[(size_t)c * (CH * CW)], w0[o * 66 + c], a);
            }
            s_alr[cell * 40 + o] = a;
        }
    }

    // ---- load weight fragments (once). Same lane layout serves A or B. ----
    f16x8 w1B, w0hB0, w0hB1;
    f16x4 w2A;  // 16x16x16 A-frag: [m=ch3=m16][k=ch2=q*4+j], rows>=8 zero
    {
        const float* p1 = w1 + m16 * 32 + q * 8;
        const float* p00 = w0 + m16 * 66 + 32 + q * 8;
        const float* p01 = w0 + (m16 + 16) * 66 + 32 + q * 8;
#pragma unroll
        for (int j = 0; j < 8; j++) {
            w1B[j] = (_Float16)p1[j];
            w0hB0[j] = (_Float16)p00[j];
            w0hB1[j] = (_Float16)p01[j];
        }
        const bool w2ok = (m16 < 8);
#pragma unroll
        for (int j = 0; j < 4; j++)
            w2A[j] = (_Float16)(w2ok ? w2[m16 * 16 + q * 4 + j] : 0.f);
    }
    // layer-1 distance weights for this lane's channels o=q*8+j, as f32x2 pairs
    f32x2 w0d0v[4], w0d1v[4];
#pragma unroll
    for (int jp = 0; jp < 4; jp++) {
        w0d0v[jp] = f32x2{w0[(q * 8 + 2 * jp) * 66 + 64], w0[(q * 8 + 2 * jp + 1) * 66 + 64]};
        w0d1v[jp] = f32x2{w0[(q * 8 + 2 * jp) * 66 + 65], w0[(q * 8 + 2 * jp + 1) * 66 + 65]};
    }
    // layer-4 weights per D3 row ch3 = q*4+r (rows >=8 are exact zeros)
    float w3c[4];
#pragma unroll
    for (int r = 0; r < 4; r++) w3c[r] = (q < 2) ? w3[q * 4 + r] : 0.f;

    // per-lane distance operand values (pixel phase xm = w%4; ym wave-uniform)
    const int xm = m16 & 3;
    const float xv = (float)(xm < 2 ? xm - 2 : xm - 1);
    const float x1 = (float)(4 - xm), x2 = (float)(xm + 1);
    const int ym = h & 3;
    const float yv = (float)(ym < 2 ? ym - 2 : ym - 1);
    const float y1 = (float)(4 - ym), y2 = (float)(ym + 1);

    _Float16* sa = s_ahr[ty];

    __syncthreads();  // s_alr staged (everything else is per-wave)

    const float* hp = hr + (size_t)b * CC * HW + (size_t)h * WW + wp0;

    // ---- Phase A, both tiles: ahr = hr . w0hr via 4 MFMAs (D[px][ch]) ----
    f16x8 aT0, aT1;
#pragma unroll
    for (int j = 0; j < 8; j++) {
        aT0[j] = (_Float16)hp[(size_t)(q * 8 + j) * HW + m16];
        aT1[j] = (_Float16)hp[(size_t)(q * 8 + j) * HW + 16 + m16];
    }
    {
        f32x4 p00 = {0.f, 0.f, 0.f, 0.f}, p01 = {0.f, 0.f, 0.f, 0.f};
        f32x4 p10 = {0.f, 0.f, 0.f, 0.f}, p11 = {0.f, 0.f, 0.f, 0.f};
        p00 = __builtin_amdgcn_mfma_f32_16x16x32_f16(aT0, w0hB0, p00, 0, 0, 0);
        p01 = __builtin_amdgcn_mfma_f32_16x16x32_f16(aT0, w0hB1, p01, 0, 0, 0);
        p10 = __builtin_amdgcn_mfma_f32_16x16x32_f16(aT1, w0hB0, p10, 0, 0, 0);
        p11 = __builtin_amdgcn_mfma_f32_16x16x32_f16(aT1, w0hB1, p11, 0, 0, 0);
#pragma unroll
        for (int r = 0; r < 4; r++) {
            const int row = q * 4 + r;
            sa[row * 40 + m16] = (_Float16)p00[r];
            sa[row * 40 + 16 + m16] = (_Float16)p01[r];
            sa[(16 + row) * 40 + m16] = (_Float16)p10[r];
            sa[(16 + row) * 40 + 16 + m16] = (_Float16)p11[r];
        }
    }
    // hoist ahr to f32 registers ONCE per tile (reused by all 9 directions)
    const f16x8 ahv0 = *(const f16x8*)&sa[m16 * 40 + q * 8];
    const f16x8 ahv1 = *(const f16x8*)&sa[(16 + m16) * 40 + q * 8];
    f32x2 ah0[4], ah1[4];
#pragma unroll
    for (int jp = 0; jp < 4; jp++) {
        ah0[jp] = f32x2{(float)ahv0[2 * jp], (float)ahv0[2 * jp + 1]};
        ah1[jp] = f32x2{(float)ahv1[2 * jp], (float)ahv1[2 * jp + 1]};
    }

    // alr halo bases per tile (FP32); per-d cell adds a compile-time offset
    // ((1+dh)*10 + (1+dw)) * 40 floats.
    const float* alp0 = &s_alr[(m16 >> 2) * 40 + q * 8];
    const float* alp1 = &s_alr[(4 + (m16 >> 2)) * 40 + q * 8];
    const int wown0 = wp0 + m16;        // this lane's pixel, tile 0 (q-uniform)
    const int wown1 = wp0 + 16 + m16;   // tile 1

    float l0[9], l1[9];
    // ---- d-grouped main loop: 3 groups x {3 directions x 2 tiles} ----
    // Phases batched so 6 independent chains share each latency shadow.
#pragma unroll
    for (int g = 0; g < 3; g++) {
        // phase 1: build 6 layer-1 A-fragments (k = ch1, n = px)
        f16x8 a1[6];
#pragma unroll
        for (int k = 0; k < 3; k++) {
            const int d = g * 3 + k;
            const int dh = K_dh[d], dw = K_dw[d];
            const float d0 = (K_s0[d] == 0) ? xv : ((K_s0[d] == 1) ? x1 : x2);
            const float d1 = (K_s1[d] == 0) ? yv : ((K_s1[d] == 1) ? y1 : y2);
            const f32x2 d0v = {d0, d0}, d1v = {d1, d1};
            const int off = ((1 + dh) * 10 + (1 + dw)) * 40;
            f32x2 dd[4];
#pragma unroll
            for (int jp = 0; jp < 4; jp++)
                dd[jp] = __builtin_elementwise_fma(w0d0v[jp], d0v, w0d1v[jp] * d1v);
            const f32x2* al0 = (const f32x2*)(alp0 + off);
            const f32x2* al1 = (const f32x2*)(alp1 + off);
#pragma unroll
            for (int jp = 0; jp < 4; jp++) {
                f32x2 v0 = ah0[jp] + al0[jp];
                f32x2 v1 = ah1[jp] + al1[jp];
                v0 = v0 + dd[jp];
                v1 = v1 + dd[jp];
                v0 = __builtin_elementwise_max(v0, v0 * 0.01f);
                v1 = __builtin_elementwise_max(v1, v1 * 0.01f);
                a1[2 * k][2 * jp] = (_Float16)v0[0];
                a1[2 * k][2 * jp + 1] = (_Float16)v0[1];
                a1[2 * k + 1][2 * jp] = (_Float16)v1[0];
                a1[2 * k + 1][2 * jp + 1] = (_Float16)v1[1];
            }
        }
        // phase 2: 6 back-to-back layer-2 MFMAs (SWAPPED: D2[ch2][px])
        f32x4 c2[6];
#pragma unroll
        for (int k = 0; k < 6; k++) {
            f32x4 z = {0.f, 0.f, 0.f, 0.f};
            c2[k] = __builtin_amdgcn_mfma_f32_16x16x32_f16(w1B, a1[k], z, 0, 0, 0);
        }
        // phase 3: glue (pure in-lane): b3 = pack(leaky(c2)), k-rows q*4+r
        f16x4 b3[6];
#pragma unroll
        for (int k = 0; k < 6; k++) {
#pragma unroll
            for (int r = 0; r < 4; r++) {
                const float e = fmaxf(c2[k][r], 0.01f * c2[k][r]);
                b3[k][r] = (_Float16)e;
            }
        }
        // phase 4: 6 back-to-back layer-3 MFMAs (16x16x16, K=16 exact)
        f32x4 c3[6];
#pragma unroll
        for (int k = 0; k < 6; k++) {
            f32x4 z = {0.f, 0.f, 0.f, 0.f};
            c3[k] = __builtin_amdgcn_mfma_f32_16x16x16f16(w2A, b3[k], z, 0, 0, 0);
        }
        // phase 5: layer-4 reduce + bounds select (6 chains)
#pragma unroll
        for (int k = 0; k < 3; k++) {
            const int d = g * 3 + k;
            const int dh = K_dh[d], dw = K_dw[d];
            const bool okh = (unsigned)(h + 4 * dh) < (unsigned)HH;
            {
                float part = 0.f;
#pragma unroll
                for (int r = 0; r < 4; r++) {
                    const float lv = fmaxf(c3[2 * k][r], 0.01f * c3[2 * k][r]);
                    part = fmaf(w3c[r], lv, part);
                }
                float s2 = part + swz_x16(part);
                const float lg = s2 + __shfl_xor(s2, 32, 64);
                const bool ok = okh && ((unsigned)(wown0 + 4 * dw) < (unsigned)WW);
                l0[d] = ok ? lg : -100.0f;
            }
            {
                float part = 0.f;
#pragma unroll
                for (int r = 0; r < 4; r++) {
                    const float lv = fmaxf(c3[2 * k + 1][r], 0.01f * c3[2 * k + 1][r]);
                    part = fmaf(w3c[r], lv, part);
                }
                float s2 = part + swz_x16(part);
                const float lg = s2 + __shfl_xor(s2, 32, 64);
                const bool ok = okh && ((unsigned)(wown1 + 4 * dw) < (unsigned)WW);
                l1[d] = ok ? lg : -100.0f;
            }
        }
    }

    // fused tail: logits replicated in all 64 lanes (DS reduce), so each
    // lane selects its own pixel's 9 logits and runs ONE softmax chain.
    // lanes 0..15 -> tile0 px wp0+lane; lanes 16..31 -> tile1 px wp0+lane.
    float ld[9];
#pragma unroll
    for (int d = 0; d < 9; d++) ld[d] = (lane & 16) ? l1[d] : l0[d];
    float mx = ld[0];
#pragma unroll
    for (int d = 1; d < 9; d++) mx = fmaxf(mx, ld[d]);
    float s = 0.f;
#pragma unroll
    for (int d = 0; d < 9; d++) {
        ld[d] = __expf(ld[d] - mx);
        s += ld[d];
    }
    const float inv = __builtin_amdgcn_rcpf(s);
    if (lane < 32) {  // 32 writer lanes -> 9 contiguous 128B stores (both tiles)
        float* op = out + (size_t)b * 9 * HW + (size_t)h * WW + (wp0 + lane);
#pragma unroll
        for (int d = 0; d < 9; d++) op[(size_t)d * HW] = ld[d] * inv;
    }
}

extern "C" void kernel_launch(void* const* d_in, const int* in_sizes, int n_in,
                              void* d_out, int out_size, void* d_ws, size_t ws_size,
                              hipStream_t stream) {
    const float* lr = (const float*)d_in[0];
    const float* hr = (const float*)d_in[1];
    // d_in[2], d_in[3] (lr_feature_r / hr_feature_r) are unused by the reference.
    const float* w0 = (const float*)d_in[4];
    const float* w1 = (const float*)d_in[5];
    const float* w2 = (const float*)d_in[6];
    const float* w3 = (const float*)d_in[7];
    float* out = (float*)d_out;

    const size_t alr_bytes = (size_t)BB * CH * CW * 32 * sizeof(float);  // 2 MB
    dim3 grid(WW / 32, HH / 4, BB);  // 2048 blocks of 256 thr (4 waves)

    if (ws_size >= alr_bytes) {
        float* alr = (float*)d_ws;
        alr_prepass<<<(BB * CH * CW + 255) / 256, 256, 0, stream>>>(lr, w0, alr);
        ercm_mfma<true><<<grid, 256, 0, stream>>>(hr, lr, alr, w0, w1, w2, w3, out);
    } else {
        ercm_mfma<false><<<grid, 256, 0, stream>>>(hr, lr, nullptr, w0, w1, w2, w3, out);
    }
}

// Round 15
// 139.606 us; speedup vs baseline: 1.0008x; 1.0008x over previous
//
#include <hip/hip_runtime.h>
#include <math.h>

#define SC 4
#define BB 2
#define CC 32
#define HH 256
#define WW 512
#define CH (HH / SC)   // 64
#define CW (WW / SC)   // 128

using f16x8 = __attribute__((ext_vector_type(8))) _Float16;
using f16x4 = __attribute__((ext_vector_type(4))) _Float16;
using f32x4 = __attribute__((ext_vector_type(4))) float;
using f32x2 = __attribute__((ext_vector_type(2))) float;

// Direction metadata (output channel order: c, l, r, t, b, lt, rt, lb, rb)
//   s0: 0 -> xv (x[w%4]), 1 -> 4-(w%4) (D1), 2 -> (w%4)+1 (D2)
//   s1: 0 -> yv (x[h%4]), 1 -> 4-(h%4) (D3), 2 -> (h%4)+1 (D4)
constexpr int K_dh[9] = {0, 0, 0, -1, 1, -1, -1, 1, 1};
constexpr int K_dw[9] = {0, -1, 1, 0, 0, -1, 1, -1, 1};
constexpr int K_s0[9] = {0, 1, 2, 0, 0, 1, 2, 0, 0};
constexpr int K_s1[9] = {0, 0, 0, 1, 2, 0, 0, 1, 2};

// LESSONS carried:
//  - R3: never force 8 waves/EU via __launch_bounds__ (allocator splits the
//    file and spills ~80MB to scratch).
//  - R7: no quad-tile (compiler rematerializes; ILP saturates at 2 chains).
//  - R10/R11/R12 bisect: multi-output inline asm whose outputs can alias
//    (two "+v" holding equal values) gets register-coalesced into a
//    self-swap -> silent wrong answers. No aliasable asm.
//  - R14: textual phase-batching is ignored by the scheduler (VGPR stayed
//    ~64); source-level instruction order cannot force chain overlap.

// Pre-pass: ALr[(b*CH+cy)*CW+cx][o] = sum_c w0[o*66+c] * lr[b][c][cy][cx]  (fp32)
__global__ __launch_bounds__(256) void alr_prepass(const float* __restrict__ lr,
                                                   const float* __restrict__ w0,
                                                   float* __restrict__ alr) {
    const int idx = blockIdx.x * 256 + threadIdx.x;
    if (idx >= BB * CH * CW) return;
    const int b = idx / (CH * CW);
    const int cell = idx - b * (CH * CW);
    const float* lp = lr + (size_t)b * CC * CH * CW + cell;
    float lv[32];
#pragma unroll
    for (int c = 0; c < 32; c++) lv[c] = lp[(size_t)c * (CH * CW)];
    float acc[32];
#pragma unroll
    for (int o = 0; o < 32; o++) {
        float a = 0.f;
#pragma unroll
        for (int c = 0; c < 32; c++) a = fmaf(lv[c], w0[o * 66 + c], a);
        acc[o] = a;
    }
    float4* op = (float4*)(alr + (size_t)idx * 32);
#pragma unroll
    for (int j = 0; j < 8; j++)
        op[j] = make_float4(acc[4 * j], acc[4 * j + 1], acc[4 * j + 2], acc[4 * j + 3]);
}

// MFMA main, R15 = R13 (best PASSING, dur 139.3) + MFMA LAYER-4.
// R13's chain tail per (d,tile) was 4x{mul,max,fma} -> ds_swizzle -> add ->
// shfl_xor -> add (2 DS round-trips on the critical path, 18x/wave). The
// layer-4 dot rides the idle MFMA pipe instead (MfmaUtil was 4%):
//   c3 = D3[ch3=q*4+r][px=m16] IS the 16x16x16 B-frag layout (k=q*4+j), so
//   b4 = (f16)leaky(c3) in-lane, then c4 = mfma_16x16x16f16(w3A, b4) with
//   w3A rows 0 AND 4 = w3 (rest 0). D rows 0/4 -> lanes 0..15 (q0,r0) and
//   16..31 (q1,r0): the logit lands in c4[0] in exactly the 32 lanes the
//   fused tail consumes. ZERO cross-lane ops; the only DS op left in the
//   d-loop is the alr ds_read.
// Numerics tripwire: w3/leaky(c3) now pass through f16; absmax predicted
// ~0.012-0.016 (threshold 0.02). If tripped, revert layer 4 to f32 reduce.
// Carried structure (R12/R13): dual-tile (2048 blocks, 256 thr, 4 waves,
// 32 px/wave), f32 s_alr, swapped layer-2 (D2[ch2][px]), in-lane K16
// layer-3 (v_mfma_f32_16x16x16f16, w2A rows>=8 zero), fused single-softmax
// tail with lane<32 contiguous stores.
template <bool USE_WS>
__global__ __launch_bounds__(256, 4) void ercm_mfma(const float* __restrict__ hr,
                                                    const float* __restrict__ lr,
                                                    const float* __restrict__ alr,
                                                    const float* __restrict__ w0,
                                                    const float* __restrict__ w1,
                                                    const float* __restrict__ w2,
                                                    const float* __restrict__ w3,
                                                    float* __restrict__ out) {
    __shared__ float    s_alr[30 * 40];     // [cell][o] FP32, 3 x 10 halo, stride 40 (160B rows)
    __shared__ _Float16 s_ahr[4][32 * 40];  // per wave: [px 0..31][o] (both tiles)

    const int tid = threadIdx.x;
    const int lane = tid & 63;
    const int ty = tid >> 6;       // wave id = h-row within block
    const int m16 = lane & 15;
    const int q = lane >> 4;       // quad
    const int bx = blockIdx.x;     // 0..15
    const int by = blockIdx.y;     // 0..63
    const int b = blockIdx.z;      // 0..1
    const int h = by * 4 + ty;
    const int wp0 = bx * 32;
    const size_t HW = (size_t)HH * WW;

    // ---- stage ALr halo tile (3 x 10 coarse cells), FP32 ----
    const int cy0 = by, cx0 = bx * 8;
    if (USE_WS) {
        for (int i = tid; i < 30 * 32; i += 256) {
            const int c = i & 31, cell = i >> 5;
            const int row = cell / 10, col = cell - row * 10;
            const int gcy = cy0 - 1 + row, gcx = cx0 - 1 + col;
            float v = 0.f;
            if ((unsigned)gcy < (unsigned)CH && (unsigned)gcx < (unsigned)CW)
                v = alr[(((size_t)b * CH + gcy) * CW + gcx) * 32 + c];
            s_alr[cell * 40 + c] = v;
        }
    } else {
        for (int i = tid; i < 30 * 32; i += 256) {
            const int o = i & 31, cell = i >> 5;
            const int row = cell / 10, col = cell - row * 10;
            const int gcy = cy0 - 1 + row, gcx = cx0 - 1 + col;
            float a = 0.f;
            if ((unsigned)gcy < (unsigned)CH && (unsigned)gcx < (unsigned)CW) {
                const float* lp = lr + (size_t)b * CC * CH * CW + (size_t)gcy * CW + gcx;
#pragma unroll
                for (int c = 0; c < 32; c++) a = fmaf(lp[(size_t)c * (CH * CW)], w0[o * 66 + c], a);
            }
            s_alr[cell * 40 + o] = a;
        }
    }

    // ---- load weight fragments (once). Same lane layout serves A or B. ----
    f16x8 w1B, w0hB0, w0hB1;
    f16x4 w2A;  // 16x16x16 A-frag: [m=ch3=m16][k=ch2=q*4+j], rows>=8 zero
    f16x4 w3A;  // 16x16x16 A-frag: rows 0 AND 4 = w3[k] (k=ch3=q*4+j, q<2), rest 0
    {
        const float* p1 = w1 + m16 * 32 + q * 8;
        const float* p00 = w0 + m16 * 66 + 32 + q * 8;
        const float* p01 = w0 + (m16 + 16) * 66 + 32 + q * 8;
#pragma unroll
        for (int j = 0; j < 8; j++) {
            w1B[j] = (_Float16)p1[j];
            w0hB0[j] = (_Float16)p00[j];
            w0hB1[j] = (_Float16)p01[j];
        }
        const bool w2ok = (m16 < 8);
        const bool w3row = ((m16 == 0) || (m16 == 4)) && (q < 2);
#pragma unroll
        for (int j = 0; j < 4; j++) {
            w2A[j] = (_Float16)(w2ok ? w2[m16 * 16 + q * 4 + j] : 0.f);
            w3A[j] = (_Float16)(w3row ? w3[q * 4 + j] : 0.f);
        }
    }
    // layer-1 distance weights for this lane's channels o=q*8+j, as f32x2 pairs
    f32x2 w0d0v[4], w0d1v[4];
#pragma unroll
    for (int jp = 0; jp < 4; jp++) {
        w0d0v[jp] = f32x2{w0[(q * 8 + 2 * jp) * 66 + 64], w0[(q * 8 + 2 * jp + 1) * 66 + 64]};
        w0d1v[jp] = f32x2{w0[(q * 8 + 2 * jp) * 66 + 65], w0[(q * 8 + 2 * jp + 1) * 66 + 65]};
    }

    // per-lane distance operand values (pixel phase xm = w%4; ym wave-uniform)
    const int xm = m16 & 3;
    const float xv = (float)(xm < 2 ? xm - 2 : xm - 1);
    const float x1 = (float)(4 - xm), x2 = (float)(xm + 1);
    const int ym = h & 3;
    const float yv = (float)(ym < 2 ? ym - 2 : ym - 1);
    const float y1 = (float)(4 - ym), y2 = (float)(ym + 1);

    _Float16* sa = s_ahr[ty];

    __syncthreads();  // s_alr staged (everything else is per-wave)

    const float* hp = hr + (size_t)b * CC * HW + (size_t)h * WW + wp0;

    // ---- Phase A, both tiles: ahr = hr . w0hr via 4 MFMAs (D[px][ch]) ----
    f16x8 aT0, aT1;
#pragma unroll
    for (int j = 0; j < 8; j++) {
        aT0[j] = (_Float16)hp[(size_t)(q * 8 + j) * HW + m16];
        aT1[j] = (_Float16)hp[(size_t)(q * 8 + j) * HW + 16 + m16];
    }
    {
        f32x4 p00 = {0.f, 0.f, 0.f, 0.f}, p01 = {0.f, 0.f, 0.f, 0.f};
        f32x4 p10 = {0.f, 0.f, 0.f, 0.f}, p11 = {0.f, 0.f, 0.f, 0.f};
        p00 = __builtin_amdgcn_mfma_f32_16x16x32_f16(aT0, w0hB0, p00, 0, 0, 0);
        p01 = __builtin_amdgcn_mfma_f32_16x16x32_f16(aT0, w0hB1, p01, 0, 0, 0);
        p10 = __builtin_amdgcn_mfma_f32_16x16x32_f16(aT1, w0hB0, p10, 0, 0, 0);
        p11 = __builtin_amdgcn_mfma_f32_16x16x32_f16(aT1, w0hB1, p11, 0, 0, 0);
#pragma unroll
        for (int r = 0; r < 4; r++) {
            const int row = q * 4 + r;
            sa[row * 40 + m16] = (_Float16)p00[r];
            sa[row * 40 + 16 + m16] = (_Float16)p01[r];
            sa[(16 + row) * 40 + m16] = (_Float16)p10[r];
            sa[(16 + row) * 40 + 16 + m16] = (_Float16)p11[r];
        }
    }
    // hoist ahr to f32 registers ONCE per tile (reused by all 9 directions)
    const f16x8 ahv0 = *(const f16x8*)&sa[m16 * 40 + q * 8];
    const f16x8 ahv1 = *(const f16x8*)&sa[(16 + m16) * 40 + q * 8];
    f32x2 ah0[4], ah1[4];
#pragma unroll
    for (int jp = 0; jp < 4; jp++) {
        ah0[jp] = f32x2{(float)ahv0[2 * jp], (float)ahv0[2 * jp + 1]};
        ah1[jp] = f32x2{(float)ahv1[2 * jp], (float)ahv1[2 * jp + 1]};
    }

    // alr halo bases per tile (FP32); per-d cell adds a compile-time offset
    // ((1+dh)*10 + (1+dw)) * 40 floats.
    const float* alp0 = &s_alr[(m16 >> 2) * 40 + q * 8];
    const float* alp1 = &s_alr[(4 + (m16 >> 2)) * 40 + q * 8];
    const int wown0 = wp0 + m16;        // this lane's pixel, tile 0 (q-uniform)
    const int wown1 = wp0 + 16 + m16;   // tile 1

    float l0[9], l1[9];
#pragma unroll
    for (int d = 0; d < 9; d++) {
        const int dh = K_dh[d], dw = K_dw[d];
        const float d0 = (K_s0[d] == 0) ? xv : ((K_s0[d] == 1) ? x1 : x2);
        const float d1 = (K_s1[d] == 0) ? yv : ((K_s1[d] == 1) ? y1 : y2);
        const f32x2 d0v = {d0, d0}, d1v = {d1, d1};
        const int off = ((1 + dh) * 10 + (1 + dw)) * 40;

        // shared per-d distance contribution (t-invariant)
        f32x2 dd[4];
#pragma unroll
        for (int jp = 0; jp < 4; jp++)
            dd[jp] = __builtin_elementwise_fma(w0d0v[jp], d0v, w0d1v[jp] * d1v);

        // layer 1 (both tiles): A1[k=ch1][n=px] = leaky(ahr + alr + dd)
        // alr FP32 in LDS: two b128 reads per tile, no cvt chain.
        const f32x2* al0 = (const f32x2*)(alp0 + off);
        const f32x2* al1 = (const f32x2*)(alp1 + off);
        f16x8 a1_0, a1_1;
#pragma unroll
        for (int jp = 0; jp < 4; jp++) {
            f32x2 v0 = ah0[jp] + al0[jp];
            f32x2 v1 = ah1[jp] + al1[jp];
            v0 = v0 + dd[jp];
            v1 = v1 + dd[jp];
            v0 = __builtin_elementwise_max(v0, v0 * 0.01f);
            v1 = __builtin_elementwise_max(v1, v1 * 0.01f);
            a1_0[2 * jp] = (_Float16)v0[0];
            a1_0[2 * jp + 1] = (_Float16)v0[1];
            a1_1[2 * jp] = (_Float16)v1[0];
            a1_1[2 * jp + 1] = (_Float16)v1[1];
        }
        // layer 2 SWAPPED: D2[ch2][px] (lane: rows ch2=q*4+r, col px=m16)
        f32x4 c2_0 = {0.f, 0.f, 0.f, 0.f}, c2_1 = {0.f, 0.f, 0.f, 0.f};
        c2_0 = __builtin_amdgcn_mfma_f32_16x16x32_f16(w1B, a1_0, c2_0, 0, 0, 0);
        c2_1 = __builtin_amdgcn_mfma_f32_16x16x32_f16(w1B, a1_1, c2_1, 0, 0, 0);

        // layer2->3 glue: pure in-lane. D2 rows ch2=q*4+r ARE the 16x16x16
        // B-frag k-rows (k=q*4+r) -> b3 = pack(leaky(c2)).
        f16x4 b3_0, b3_1;
#pragma unroll
        for (int r = 0; r < 4; r++) {
            const float e0 = fmaxf(c2_0[r], 0.01f * c2_0[r]);
            const float e1 = fmaxf(c2_1[r], 0.01f * c2_1[r]);
            b3_0[r] = (_Float16)e0;
            b3_1[r] = (_Float16)e1;
        }
        // layer 3 (16x16x16, K=ch2=16 exact): D3[ch3=q*4+r][px=m16];
        // rows ch3>=8 exact 0 (w2A rows zero)
        f32x4 c3_0 = {0.f, 0.f, 0.f, 0.f}, c3_1 = {0.f, 0.f, 0.f, 0.f};
        c3_0 = __builtin_amdgcn_mfma_f32_16x16x16f16(w2A, b3_0, c3_0, 0, 0, 0);
        c3_1 = __builtin_amdgcn_mfma_f32_16x16x16f16(w2A, b3_1, c3_1, 0, 0, 0);

        // layer 4 via MFMA (idle pipe): b4 = (f16)leaky(c3) is already the
        // 16x16x16 B-frag (k=ch3=q*4+r rows); w3A rows 0/4 = w3 -> logit in
        // c4[0] for lanes 0..15 (tile-row 0) and 16..31 (tile-row 4).
        // No cross-lane ops.
        f16x4 b4_0, b4_1;
#pragma unroll
        for (int r = 0; r < 4; r++) {
            b4_0[r] = (_Float16)fmaxf(c3_0[r], 0.01f * c3_0[r]);
            b4_1[r] = (_Float16)fmaxf(c3_1[r], 0.01f * c3_1[r]);
        }
        f32x4 c4_0 = {0.f, 0.f, 0.f, 0.f}, c4_1 = {0.f, 0.f, 0.f, 0.f};
        c4_0 = __builtin_amdgcn_mfma_f32_16x16x16f16(w3A, b4_0, c4_0, 0, 0, 0);
        c4_1 = __builtin_amdgcn_mfma_f32_16x16x16f16(w3A, b4_1, c4_1, 0, 0, 0);

        const bool okh = (unsigned)(h + 4 * dh) < (unsigned)HH;
        {
            const bool ok = okh && ((unsigned)(wown0 + 4 * dw) < (unsigned)WW);
            l0[d] = ok ? c4_0[0] : -100.0f;
        }
        {
            const bool ok = okh && ((unsigned)(wown1 + 4 * dw) < (unsigned)WW);
            l1[d] = ok ? c4_1[0] : -100.0f;
        }
    }

    // fused tail: logits live in c4[0] for lanes 0..31 (rows 0 and 4 of the
    // w3A matmul). Each lane selects its own pixel's 9 logits and runs ONE
    // softmax chain. lanes 0..15 -> tile0 px wp0+lane; 16..31 -> tile1.
    float ld[9];
#pragma unroll
    for (int d = 0; d < 9; d++) ld[d] = (lane & 16) ? l1[d] : l0[d];
    float mx = ld[0];
#pragma unroll
    for (int d = 1; d < 9; d++) mx = fmaxf(mx, ld[d]);
    float s = 0.f;
#pragma unroll
    for (int d = 0; d < 9; d++) {
        ld[d] = __expf(ld[d] - mx);
        s += ld[d];
    }
    const float inv = __builtin_amdgcn_rcpf(s);
    if (lane < 32) {  // 32 writer lanes -> 9 contiguous 128B stores (both tiles)
        float* op = out + (size_t)b * 9 * HW + (size_t)h * WW + (wp0 + lane);
#pragma unroll
        for (int d = 0; d < 9; d++) op[(size_t)d * HW] = ld[d] * inv;
    }
}

extern "C" void kernel_launch(void* const* d_in, const int* in_sizes, int n_in,
                              void* d_out, int out_size, void* d_ws, size_t ws_size,
                              hipStream_t stream) {
    const float* lr = (const float*)d_in[0];
    const float* hr = (const float*)d_in[1];
    // d_in[2], d_in[3] (lr_feature_r / hr_feature_r) are unused by the reference.
    const float* w0 = (const float*)d_in[4];
    const float* w1 = (const float*)d_in[5];
    const float* w2 = (const float*)d_in[6];
    const float* w3 = (const float*)d_in[7];
    float* out = (float*)d_out;

    const size_t alr_bytes = (size_t)BB * CH * CW * 32 * sizeof(float);  // 2 MB
    dim3 grid(WW / 32, HH / 4, BB);  // 2048 blocks of 256 thr (4 waves)

    if (ws_size >= alr_bytes) {
        float* alr = (float*)d_ws;
        alr_prepass<<<(BB * CH * CW + 255) / 256, 256, 0, stream>>>(lr, w0, alr);
        ercm_mfma<true><<<grid, 256, 0, stream>>>(hr, lr, alr, w0, w1, w2, w3, out);
    } else {
        ercm_mfma<false><<<grid, 256, 0, stream>>>(hr, lr, nullptr, w0, w1, w2, w3, out);
    }
}